// Round 13
// baseline (357.751 us; speedup 1.0000x reference)
//
#include <hip/hip_runtime.h>
#include <stdint.h>

#define TSEQ 1024
#define DDIM 512

typedef __attribute__((ext_vector_type(8))) short bf16x8;
typedef __attribute__((ext_vector_type(4))) float f32x4;

#define MFMA(a, b, c) __builtin_amdgcn_mfma_f32_16x16x32_bf16((a), (b), (c), 0, 0, 0)

__device__ __forceinline__ unsigned short f2bf(float f) {
  unsigned int u = __builtin_bit_cast(unsigned int, f);
  u += 0x7FFFu + ((u >> 16) & 1u);
  return (unsigned short)(u >> 16);
}

__device__ __forceinline__ void async_load16(const void* g, void* l) {
  __builtin_amdgcn_global_load_lds(
      (const __attribute__((address_space(1))) unsigned int*)g,
      (__attribute__((address_space(3))) unsigned int*)l, 16, 0, 0);
}

// ---------------- LayerNorm: x[65536][512] f32 -> nx bf16 ----------------
__global__ __launch_bounds__(256) void k_ln(const float* __restrict__ x,
                                            const float* __restrict__ gamma,
                                            const float* __restrict__ beta,
                                            unsigned short* __restrict__ nx) {
  const int wid = threadIdx.x >> 6, lane = threadIdx.x & 63;
  const long long row = (long long)blockIdx.x * 4 + wid;
  const float* xr = x + row * DDIM + lane * 8;
  float4 a = *(const float4*)xr;
  float4 b = *(const float4*)(xr + 4);
  float s = a.x + a.y + a.z + a.w + b.x + b.y + b.z + b.w;
  float s2 = a.x * a.x + a.y * a.y + a.z * a.z + a.w * a.w +
             b.x * b.x + b.y * b.y + b.z * b.z + b.w * b.w;
#pragma unroll
  for (int m = 1; m < 64; m <<= 1) {
    s += __shfl_xor(s, m);
    s2 += __shfl_xor(s2, m);
  }
  const float mu = s * (1.0f / DDIM);
  const float var = s2 * (1.0f / DDIM) - mu * mu;
  const float rsd = rsqrtf(var + 1e-5f);
  const float4 g0 = *(const float4*)(gamma + lane * 8);
  const float4 g1 = *(const float4*)(gamma + lane * 8 + 4);
  const float4 b0 = *(const float4*)(beta + lane * 8);
  const float4 b1 = *(const float4*)(beta + lane * 8 + 4);
  float o0 = (a.x - mu) * rsd * g0.x + b0.x;
  float o1 = (a.y - mu) * rsd * g0.y + b0.y;
  float o2 = (a.z - mu) * rsd * g0.z + b0.z;
  float o3 = (a.w - mu) * rsd * g0.w + b0.w;
  float o4 = (b.x - mu) * rsd * g1.x + b1.x;
  float o5 = (b.y - mu) * rsd * g1.y + b1.y;
  float o6 = (b.z - mu) * rsd * g1.z + b1.z;
  float o7 = (b.w - mu) * rsd * g1.w + b1.w;
  uint4 pk;
  pk.x = f2bf(o0) | ((unsigned)f2bf(o1) << 16);
  pk.y = f2bf(o2) | ((unsigned)f2bf(o3) << 16);
  pk.z = f2bf(o4) | ((unsigned)f2bf(o5) << 16);
  pk.w = f2bf(o6) | ((unsigned)f2bf(o7) << 16);
  *(uint4*)(nx + row * DDIM + lane * 8) = pk;
}

// ---------------- cast Wg f32 -> bf16 ----------------
__global__ __launch_bounds__(256) void k_cast(const float* __restrict__ w,
                                              unsigned short* __restrict__ o, int n8) {
  const int i = blockIdx.x * 256 + threadIdx.x;
  if (i >= n8) return;
  const float4 a = *(const float4*)(w + (size_t)i * 8);
  const float4 b = *(const float4*)(w + (size_t)i * 8 + 4);
  uint4 pk;
  pk.x = f2bf(a.x) | ((unsigned)f2bf(a.y) << 16);
  pk.y = f2bf(a.z) | ((unsigned)f2bf(a.w) << 16);
  pk.z = f2bf(b.x) | ((unsigned)f2bf(b.y) << 16);
  pk.w = f2bf(b.z) | ((unsigned)f2bf(b.w) << 16);
  *(uint4*)(o + (size_t)i * 8) = pk;
}

// ---------------- GEMM + fused V-fragment transpose (verified R7/R8) -------
__global__ __launch_bounds__(256, 2) void k_gemm(const unsigned short* __restrict__ A,
                                                 const unsigned short* __restrict__ B,
                                                 unsigned short* __restrict__ C,
                                                 unsigned short* __restrict__ W) {
  __shared__ char sbuf[33280];  // staging 32KB; epilogue tb[128][130] bf16
  char* As = sbuf;
  char* Bs = sbuf + 16384;
  const int tid = threadIdx.x;
  const int wid = tid >> 6, lane = tid & 63;
  const int g = lane >> 4, c = lane & 15;
  const int wr = wid >> 1, wc = wid & 1;
  const int bm = blockIdx.y, bn = blockIdx.x;

  int srcoff[4], ldsoff[4];
#pragma unroll
  for (int r = 0; r < 4; ++r) {
    const int aoff = r * 4096 + tid * 16;
    srcoff[r] = (aoff >> 7) * 1024 + (aoff & 127);
    ldsoff[r] = r * 4096 + (wid << 10);
  }
  const char* Ab = (const char*)A + (size_t)bm * 131072;
  const char* Bb = (const char*)B + (size_t)bn * 131072;

  f32x4 acc[4][4] = {};

  for (int ks = 0; ks < 8; ++ks) {
    __syncthreads();
#pragma unroll
    for (int r = 0; r < 4; ++r) {
      async_load16(Ab + ks * 128 + srcoff[r], As + ldsoff[r]);
      async_load16(Bb + ks * 128 + srcoff[r], Bs + ldsoff[r]);
    }
    __syncthreads();
    bf16x8 af[4][2], bfr[4][2];
#pragma unroll
    for (int f = 0; f < 4; ++f) {
#pragma unroll
      for (int kk = 0; kk < 2; ++kk) {
        const int rowa = wr * 64 + f * 16 + c;
        af[f][kk] = *(const bf16x8*)(As + rowa * 128 + (kk * 4 + g) * 16);
        const int rowb = wc * 64 + f * 16 + c;
        bfr[f][kk] = *(const bf16x8*)(Bs + rowb * 128 + (kk * 4 + g) * 16);
      }
    }
#pragma unroll
    for (int i = 0; i < 4; ++i) {
#pragma unroll
      for (int j = 0; j < 4; ++j) {
        acc[i][j] = MFMA(af[i][0], bfr[j][0], acc[i][j]);
        acc[i][j] = MFMA(af[i][1], bfr[j][1], acc[i][j]);
      }
    }
  }

  // ---- C write (row-major qkv)
#pragma unroll
  for (int i = 0; i < 4; ++i) {
#pragma unroll
    for (int r = 0; r < 4; ++r) {
      const long long row = (long long)bm * 128 + wr * 64 + i * 16 + g * 4 + r;
#pragma unroll
      for (int j = 0; j < 4; ++j) {
        const int col = bn * 128 + wc * 64 + j * 16 + c;
        C[row * DDIM + col] = f2bf(acc[i][j][r]);
      }
    }
  }

  // ---- W write via LDS transpose (tb stride 130 elems)
  __syncthreads();  // all staging-LDS reads done before overwrite
  unsigned short* tb = (unsigned short*)sbuf;
#pragma unroll
  for (int i = 0; i < 4; ++i)
#pragma unroll
    for (int j = 0; j < 4; ++j)
#pragma unroll
      for (int r = 0; r < 4; ++r)
        tb[(wr * 64 + i * 16 + g * 4 + r) * 130 + wc * 64 + j * 16 + c] =
            f2bf(acc[i][j][r]);
  __syncthreads();
  const int bc = bm >> 3;
  const int kvt = (bm & 7) * 4 + wid;  // wave owns one kv-subtile (32 rows)
#pragma unroll
  for (int dt_l = 0; dt_l < 8; ++dt_l) {
    const int d_l = dt_l * 16 + c;
    const int kv0 = wid * 32 + g * 8;
    bf16x8 v;
#pragma unroll
    for (int j = 0; j < 8; ++j) v[j] = tb[(kv0 + j) * 130 + d_l];
    const size_t woff =
        ((((size_t)bc * 32 + kvt) * 32) + bn * 8 + dt_l) * 1024 + lane * 16;
    *(bf16x8*)((char*)W + woff) = v;
  }
}

// ---------------- Flash attention (causal), Q=K=V=qkv, + residual add --------
// R13 = R11 (verified 2-barrier structure) + two barrier-local micro-opts:
// (1) V reads hoisted above barrier B: V(kvt) was staged last iteration and
//     drained at barrier A; nothing writes vbuf[kvt&1] this iteration (staging
//     targets (kvt+1)&1). Their latency hides under the whole phase-1 stretch,
//     shortening the post-B serial tail to P-reads + MFMA.
// (2) setprio(1) around the PV MFMA cluster (waves are desynced around B by
//     the divergent phase-1 skip).
__global__ __launch_bounds__(512, 2) void k_attn(const unsigned short* __restrict__ qkv,
                                                 const unsigned short* __restrict__ W,
                                                 const float* __restrict__ x,
                                                 float* __restrict__ xo) {
  __shared__ char lds[139776];  // K dbuf 64K | V dbuf 64K | P 8K | ldenom 512B
  char* Pb = lds + 131072;
  float* ldenom = (float*)(lds + 139264);
  const int tid = threadIdx.x;
  const int wid = tid >> 6, lane = tid & 63;
  const int g = lane >> 4, c = lane & 15;
  const int bc = blockIdx.x;
  const size_t bcbase = (size_t)bc * TSEQ * DDIM;
  const float K1 = 0.0637587155f;  // (512^-0.5) * log2(e)
  const float K2 = -11.5415603f;   // -8 * log2(e)

  // P slot offset (conflict-free slot-XOR; same formula on write/read)
  const int poff = c * 64 + ((g ^ ((c >> 1) & 3)) << 4);

  // QK K-read offsets (R6-verified): row(ft,c), kappa swizzle
  int e0[2], e1[2];
#pragma unroll
  for (int ft = 0; ft < 2; ++ft) {
    const int row = ((c >> 2) << 3) + (ft << 2) + (c & 3);
    const int kap = ((ft << 2) | (c & 3)) ^ ((c >> 2) << 1);
    e0[ft] = row * 1024 + ((g ^ kap) << 4);
    e1[ft] = row * 1024 + (((4 + g) ^ kap) << 4);
  }

  // K staging offsets (kappa-preswizzled source)
  int soffK[4];
#pragma unroll
  for (int r = 0; r < 4; ++r) {
    const int row = wid * 4 + r;
    const int kap = (row & 7) ^ (((row >> 3) & 3) << 1);
    soffK[r] = row * 1024 + ((lane ^ kap) << 4);
  }
  const char* kgb = (const char*)(qkv + bcbase);
  const char* wtb = (const char*)W + ((size_t)bc << 20);

#pragma unroll 1
  for (int h = 0; h < 2; ++h) {
    const int qt = h == 0 ? 7 - blockIdx.y : blockIdx.y;
    const int qrow = qt * 128 + wid * 16 + c;
    const int wave_qmin = qt * 128 + wid * 16;
    const int NT = 4 * qt + 4;

    // Q fragments: lane holds Q[q = c][d = ks*32 + g*8 + j]
    bf16x8 qf[16];
    const unsigned short* qp = qkv + bcbase + (size_t)qrow * DDIM + g * 8;
#pragma unroll
    for (int ks = 0; ks < 16; ++ks) qf[ks] = *(const bf16x8*)(qp + ks * 32);

    f32x4 oacc[8][4] = {};  // O[q = qg*16 + g*4 + r][d = wid*64 + dtl*16 + c]
    float lrun = 0.0f;

    {  // prologue: stage tile 0 -> buf 0 (K swizzled; V linear from W)
      char* kb = lds;
      char* vb = lds + 65536;
#pragma unroll
      for (int r = 0; r < 4; ++r) {
        async_load16(kgb + soffK[r], kb + wid * 4096 + r * 1024 + lane * 16);
        async_load16(wtb + r * 8192 + tid * 16, vb + r * 8192 + (wid << 10));
      }
    }

    for (int kvt = 0; kvt < NT; ++kvt) {
      __syncthreads();  // A: buf[kvt&1] staged; prior P reads done
      const char* kb = lds + (kvt & 1) * 32768;
      const char* vb = lds + 65536 + (kvt & 1) * 32768;

      if (kvt + 1 < NT) {  // stage next tile; latency hides under QK phase
        char* kd = lds + ((kvt + 1) & 1) * 32768;
        char* vd = lds + 65536 + ((kvt + 1) & 1) * 32768;
        const char* ksrc = kgb + (kvt + 1) * 32768;
        const char* vsrc = wtb + (size_t)(kvt + 1) * 32768;
#pragma unroll
        for (int r = 0; r < 4; ++r) {
          async_load16(ksrc + soffK[r], kd + wid * 4096 + r * 1024 + lane * 16);
          async_load16(vsrc + r * 8192 + tid * 16, vd + r * 8192 + (wid << 10));
        }
      }

      // ---- V reads for phase 2, hoisted: vbuf[kvt&1] valid since barrier A
      // and not written this iteration; latency hides under phase 1.
      const char* vp = vb + wid * 4096 + lane * 16;
      const bf16x8 v0 = *(const bf16x8*)(vp);
      const bf16x8 v1 = *(const bf16x8*)(vp + 1024);
      const bf16x8 v2 = *(const bf16x8*)(vp + 2048);
      const bf16x8 v3 = *(const bf16x8*)(vp + 3072);

      // ---- Phase 1: QK + fixed-shift softmax + P write (own 16 q-rows)
      if (kvt * 32 <= wave_qmin + 15) {
        f32x4 stA[2] = {}, stB[2] = {};
        __builtin_amdgcn_s_setprio(1);
#pragma unroll
        for (int ks = 0; ks < 8; ++ks) {
          const int imm = (ks >> 1) * 128;
#pragma unroll
          for (int ft = 0; ft < 2; ++ft) {
            const bf16x8 kf = *(const bf16x8*)(kb + imm + ((ks & 1) ? e1[ft] : e0[ft]));
            stA[ft] = MFMA(kf, qf[ks], stA[ft]);
          }
        }
#pragma unroll
        for (int ks = 8; ks < 16; ++ks) {
          const int imm = (ks >> 1) * 128;
#pragma unroll
          for (int ft = 0; ft < 2; ++ft) {
            const bf16x8 kf = *(const bf16x8*)(kb + imm + ((ks & 1) ? e1[ft] : e0[ft]));
            stB[ft] = MFMA(kf, qf[ks], stB[ft]);
          }
        }
        __builtin_amdgcn_s_setprio(0);
        f32x4 st[2];
        st[0] = stA[0] + stB[0];
        st[1] = stA[1] + stB[1];

        float ex[2][4];
        if (kvt * 32 + 31 <= wave_qmin) {  // fully unmasked for all 16 rows
#pragma unroll
          for (int ft = 0; ft < 2; ++ft)
#pragma unroll
            for (int r = 0; r < 4; ++r)
              ex[ft][r] = exp2f(fmaf(st[ft][r], K1, K2));
        } else {  // diagonal tile: per-element causal mask
#pragma unroll
          for (int ft = 0; ft < 2; ++ft)
#pragma unroll
            for (int r = 0; r < 4; ++r) {
              const int kvg = kvt * 32 + g * 8 + ft * 4 + r;
              ex[ft][r] = (kvg > qrow) ? 0.0f : exp2f(fmaf(st[ft][r], K1, K2));
            }
        }
#pragma unroll
        for (int ft = 0; ft < 2; ++ft)
#pragma unroll
          for (int r = 0; r < 4; ++r) lrun += ex[ft][r];

        bf16x8 pa0;  // pa0[i] = P[q = c][kv = g*8 + i]
#pragma unroll
        for (int r = 0; r < 4; ++r) {
          pa0[r] = (short)f2bf(ex[0][r]);
          pa0[r + 4] = (short)f2bf(ex[1][r]);
        }
        *(bf16x8*)(Pb + wid * 1024 + poff) = pa0;
      }

      __syncthreads();  // B: P visible to all waves

      // ---- Phase 2: PV for d-slice [wid*64, wid*64+64) over all 128 q
      __builtin_amdgcn_s_setprio(1);
#pragma unroll
      for (int qg = 0; qg < 8; ++qg) {
        if (qt * 128 + qg * 16 + 15 >= kvt * 32) {  // qg has live rows
          const bf16x8 pa = *(const bf16x8*)(Pb + qg * 1024 + poff);
          oacc[qg][0] = MFMA(pa, v0, oacc[qg][0]);
          oacc[qg][1] = MFMA(pa, v1, oacc[qg][1]);
          oacc[qg][2] = MFMA(pa, v2, oacc[qg][2]);
          oacc[qg][3] = MFMA(pa, v3, oacc[qg][3]);
        }
      }
      __builtin_amdgcn_s_setprio(0);
    }

    // ---- epilogue: share denominators, then x + O/l
    float lr = lrun;
    lr += __shfl_xor(lr, 16);
    lr += __shfl_xor(lr, 32);
    if (lane < 16) ldenom[wid * 16 + lane] = 1.0f / lr;
    __syncthreads();
#pragma unroll
    for (int qg = 0; qg < 8; ++qg) {
#pragma unroll
      for (int r = 0; r < 4; ++r) {
        const float rv = ldenom[qg * 16 + g * 4 + r];
        const size_t rb =
            bcbase + (size_t)(qt * 128 + qg * 16 + g * 4 + r) * DDIM + wid * 64 + c;
#pragma unroll
        for (int dtl = 0; dtl < 4; ++dtl) {
          const size_t off = rb + dtl * 16;
          xo[off] = x[off] + oacc[qg][dtl][r] * rv;
        }
      }
    }
    __syncthreads();  // all LDS reads of half h done before half h+1 reuse
  }
}

// ---------------- cell mixing + sin pulse (in-place on d_out) ----------------
__global__ __launch_bounds__(256) void k_mix(float* __restrict__ xo,
                                             const float* __restrict__ inh,
                                             const float* __restrict__ phz,
                                             const float* __restrict__ rsc) {
  __shared__ float sI[256];
  __shared__ float sP[16];
  const int tid = threadIdx.x;
  sI[tid] = inh[tid];
  if (tid < 16) sP[tid] = phz[tid];
  __syncthreads();
  const float rs = rsc[0];
  const int idx = blockIdx.x * 256 + tid;
  const int d4 = idx & 127;
  const int t = (idx >> 7) & 1023;
  const int b = idx >> 17;
  float4* base = (float4*)xo + ((size_t)b * 16 * TSEQ + t) * 128 + d4;
  float4 v[16];
#pragma unroll
  for (int cc = 0; cc < 16; ++cc) v[cc] = base[(size_t)cc * TSEQ * 128];
#pragma unroll
  for (int k = 0; k < 16; ++k) {
    float4 comp = make_float4(0.f, 0.f, 0.f, 0.f);
#pragma unroll
    for (int cc = 0; cc < 16; ++cc) {
      const float w = sI[cc * 16 + k];
      comp.x += v[cc].x * w;
      comp.y += v[cc].y * w;
      comp.z += v[cc].z * w;
      comp.w += v[cc].w * w;
    }
    const float ph = sP[k];
    float4 o;
    o.x = v[k].x + __sinf(comp.x + ph) * rs;
    o.y = v[k].y + __sinf(comp.y + ph) * rs;
    o.z = v[k].z + __sinf(comp.z + ph) * rs;
    o.w = v[k].w + __sinf(comp.w + ph) * rs;
    base[(size_t)k * TSEQ * 128] = o;
  }
}

extern "C" void kernel_launch(void* const* d_in, const int* in_sizes, int n_in,
                              void* d_out, int out_size, void* d_ws, size_t ws_size,
                              hipStream_t stream) {
  const float* x = (const float*)d_in[0];
  // d_in[1] = causal mask -- implemented analytically
  const float* gamma = (const float*)d_in[2];
  const float* beta = (const float*)d_in[3];
  const float* Wg = (const float*)d_in[4];
  const float* inh = (const float*)d_in[5];
  const float* phz = (const float*)d_in[6];
  const float* rsc = (const float*)d_in[7];
  float* out = (float*)d_out;

  // ws (>=128MiB, confirmed): qkv (64MiB) + W (64MiB, V in PV-fragment order).
  // nx -> d_out[0:64MiB); wgb -> d_out @100MiB (dead before k_attn writes).
  unsigned short* qkv = (unsigned short*)d_ws;
  unsigned short* W = qkv + (size_t)33554432;
  unsigned short* nx = (unsigned short*)d_out;
  unsigned short* wgb = (unsigned short*)((char*)d_out + 104857600);

  k_cast<<<128, 256, 0, stream>>>(Wg, wgb, 32768);
  k_ln<<<16384, 256, 0, stream>>>(x, gamma, beta, nx);
  k_gemm<<<dim3(4, 512), 256, 0, stream>>>(nx, wgb, qkv, W);
  k_attn<<<dim3(64, 4), 512, 0, stream>>>(qkv, W, x, out);
  k_mix<<<2048, 256, 0, stream>>>(out, inh, phz, rsc);
}

// Round 14
// 298.234 us; speedup vs baseline: 1.1996x; 1.1996x over previous
//
#include <hip/hip_runtime.h>
#include <stdint.h>

#define TSEQ 1024
#define DDIM 512

typedef __attribute__((ext_vector_type(8))) short bf16x8;
typedef __attribute__((ext_vector_type(4))) float f32x4;

#define MFMA(a, b, c) __builtin_amdgcn_mfma_f32_16x16x32_bf16((a), (b), (c), 0, 0, 0)

__device__ __forceinline__ unsigned short f2bf(float f) {
  unsigned int u = __builtin_bit_cast(unsigned int, f);
  u += 0x7FFFu + ((u >> 16) & 1u);
  return (unsigned short)(u >> 16);
}

__device__ __forceinline__ void async_load16(const void* g, void* l) {
  __builtin_amdgcn_global_load_lds(
      (const __attribute__((address_space(1))) unsigned int*)g,
      (__attribute__((address_space(3))) unsigned int*)l, 16, 0, 0);
}

// ---------------- LayerNorm: x[65536][512] f32 -> nx bf16 ----------------
__global__ __launch_bounds__(256) void k_ln(const float* __restrict__ x,
                                            const float* __restrict__ gamma,
                                            const float* __restrict__ beta,
                                            unsigned short* __restrict__ nx) {
  const int wid = threadIdx.x >> 6, lane = threadIdx.x & 63;
  const long long row = (long long)blockIdx.x * 4 + wid;
  const float* xr = x + row * DDIM + lane * 8;
  float4 a = *(const float4*)xr;
  float4 b = *(const float4*)(xr + 4);
  float s = a.x + a.y + a.z + a.w + b.x + b.y + b.z + b.w;
  float s2 = a.x * a.x + a.y * a.y + a.z * a.z + a.w * a.w +
             b.x * b.x + b.y * b.y + b.z * b.z + b.w * b.w;
#pragma unroll
  for (int m = 1; m < 64; m <<= 1) {
    s += __shfl_xor(s, m);
    s2 += __shfl_xor(s2, m);
  }
  const float mu = s * (1.0f / DDIM);
  const float var = s2 * (1.0f / DDIM) - mu * mu;
  const float rsd = rsqrtf(var + 1e-5f);
  const float4 g0 = *(const float4*)(gamma + lane * 8);
  const float4 g1 = *(const float4*)(gamma + lane * 8 + 4);
  const float4 b0 = *(const float4*)(beta + lane * 8);
  const float4 b1 = *(const float4*)(beta + lane * 8 + 4);
  float o0 = (a.x - mu) * rsd * g0.x + b0.x;
  float o1 = (a.y - mu) * rsd * g0.y + b0.y;
  float o2 = (a.z - mu) * rsd * g0.z + b0.z;
  float o3 = (a.w - mu) * rsd * g0.w + b0.w;
  float o4 = (b.x - mu) * rsd * g1.x + b1.x;
  float o5 = (b.y - mu) * rsd * g1.y + b1.y;
  float o6 = (b.z - mu) * rsd * g1.z + b1.z;
  float o7 = (b.w - mu) * rsd * g1.w + b1.w;
  uint4 pk;
  pk.x = f2bf(o0) | ((unsigned)f2bf(o1) << 16);
  pk.y = f2bf(o2) | ((unsigned)f2bf(o3) << 16);
  pk.z = f2bf(o4) | ((unsigned)f2bf(o5) << 16);
  pk.w = f2bf(o6) | ((unsigned)f2bf(o7) << 16);
  *(uint4*)(nx + row * DDIM + lane * 8) = pk;
}

// ---------------- cast Wg f32 -> bf16 ----------------
__global__ __launch_bounds__(256) void k_cast(const float* __restrict__ w,
                                              unsigned short* __restrict__ o, int n8) {
  const int i = blockIdx.x * 256 + threadIdx.x;
  if (i >= n8) return;
  const float4 a = *(const float4*)(w + (size_t)i * 8);
  const float4 b = *(const float4*)(w + (size_t)i * 8 + 4);
  uint4 pk;
  pk.x = f2bf(a.x) | ((unsigned)f2bf(a.y) << 16);
  pk.y = f2bf(a.z) | ((unsigned)f2bf(a.w) << 16);
  pk.z = f2bf(b.x) | ((unsigned)f2bf(b.y) << 16);
  pk.w = f2bf(b.z) | ((unsigned)f2bf(b.w) << 16);
  *(uint4*)(o + (size_t)i * 8) = pk;
}

// ---------------- GEMM + fused V-fragment transpose (verified R7/R8) -------
// R14: 1D grid with XCD-aware mapping: wg = ((bm>>3)*4 + bn)*8 + (bm&7) ->
// the 4 same-bm blocks (sharing the A-tile) land on the SAME XCD (wgid mod 8
// equal) and adjacent in time (spaced 8) -> A refetches become L2 hits.
// Bijective for nwg=2048. Per-block work identical to R11.
__global__ __launch_bounds__(256, 2) void k_gemm(const unsigned short* __restrict__ A,
                                                 const unsigned short* __restrict__ B,
                                                 unsigned short* __restrict__ C,
                                                 unsigned short* __restrict__ W) {
  __shared__ char sbuf[33280];  // staging 32KB; epilogue tb[128][130] bf16
  char* As = sbuf;
  char* Bs = sbuf + 16384;
  const int tid = threadIdx.x;
  const int wid = tid >> 6, lane = tid & 63;
  const int g = lane >> 4, c = lane & 15;
  const int wr = wid >> 1, wc = wid & 1;
  const int wg = blockIdx.x;
  const int bm = ((wg >> 5) << 3) | (wg & 7);  // slot*8 + xcd
  const int bn = (wg >> 3) & 3;

  int srcoff[4], ldsoff[4];
#pragma unroll
  for (int r = 0; r < 4; ++r) {
    const int aoff = r * 4096 + tid * 16;
    srcoff[r] = (aoff >> 7) * 1024 + (aoff & 127);
    ldsoff[r] = r * 4096 + (wid << 10);
  }
  const char* Ab = (const char*)A + (size_t)bm * 131072;
  const char* Bb = (const char*)B + (size_t)bn * 131072;

  f32x4 acc[4][4] = {};

  for (int ks = 0; ks < 8; ++ks) {
    __syncthreads();
#pragma unroll
    for (int r = 0; r < 4; ++r) {
      async_load16(Ab + ks * 128 + srcoff[r], As + ldsoff[r]);
      async_load16(Bb + ks * 128 + srcoff[r], Bs + ldsoff[r]);
    }
    __syncthreads();
    bf16x8 af[4][2], bfr[4][2];
#pragma unroll
    for (int f = 0; f < 4; ++f) {
#pragma unroll
      for (int kk = 0; kk < 2; ++kk) {
        const int rowa = wr * 64 + f * 16 + c;
        af[f][kk] = *(const bf16x8*)(As + rowa * 128 + (kk * 4 + g) * 16);
        const int rowb = wc * 64 + f * 16 + c;
        bfr[f][kk] = *(const bf16x8*)(Bs + rowb * 128 + (kk * 4 + g) * 16);
      }
    }
#pragma unroll
    for (int i = 0; i < 4; ++i) {
#pragma unroll
      for (int j = 0; j < 4; ++j) {
        acc[i][j] = MFMA(af[i][0], bfr[j][0], acc[i][j]);
        acc[i][j] = MFMA(af[i][1], bfr[j][1], acc[i][j]);
      }
    }
  }

  // ---- C write (row-major qkv)
#pragma unroll
  for (int i = 0; i < 4; ++i) {
#pragma unroll
    for (int r = 0; r < 4; ++r) {
      const long long row = (long long)bm * 128 + wr * 64 + i * 16 + g * 4 + r;
#pragma unroll
      for (int j = 0; j < 4; ++j) {
        const int col = bn * 128 + wc * 64 + j * 16 + c;
        C[row * DDIM + col] = f2bf(acc[i][j][r]);
      }
    }
  }

  // ---- W write via LDS transpose (tb stride 130 elems)
  __syncthreads();  // all staging-LDS reads done before overwrite
  unsigned short* tb = (unsigned short*)sbuf;
#pragma unroll
  for (int i = 0; i < 4; ++i)
#pragma unroll
    for (int j = 0; j < 4; ++j)
#pragma unroll
      for (int r = 0; r < 4; ++r)
        tb[(wr * 64 + i * 16 + g * 4 + r) * 130 + wc * 64 + j * 16 + c] =
            f2bf(acc[i][j][r]);
  __syncthreads();
  const int bc = bm >> 3;
  const int kvt = (bm & 7) * 4 + wid;  // wave owns one kv-subtile (32 rows)
#pragma unroll
  for (int dt_l = 0; dt_l < 8; ++dt_l) {
    const int d_l = dt_l * 16 + c;
    const int kv0 = wid * 32 + g * 8;
    bf16x8 v;
#pragma unroll
    for (int j = 0; j < 8; ++j) v[j] = tb[(kv0 + j) * 130 + d_l];
    const size_t woff =
        ((((size_t)bc * 32 + kvt) * 32) + bn * 8 + dt_l) * 1024 + lane * 16;
    *(bf16x8*)((char*)W + woff) = v;
  }
}

// ---------------- Flash attention (causal), Q=K=V=qkv, + residual add --------
// R14 attn = exact R11 (verified: 151us, absmax 0.03125). d-split PV + P via
// LDS; 2 barriers/tile; fixed-shift softmax; kappa-swizzled K; V from W in
// PV-fragment order (bank-balanced linear reads).
__global__ __launch_bounds__(512, 2) void k_attn(const unsigned short* __restrict__ qkv,
                                                 const unsigned short* __restrict__ W,
                                                 const float* __restrict__ x,
                                                 float* __restrict__ xo) {
  __shared__ char lds[139776];  // K dbuf 64K | V dbuf 64K | P 8K | ldenom 512B
  char* Pb = lds + 131072;
  float* ldenom = (float*)(lds + 139264);
  const int tid = threadIdx.x;
  const int wid = tid >> 6, lane = tid & 63;
  const int g = lane >> 4, c = lane & 15;
  const int bc = blockIdx.x;
  const size_t bcbase = (size_t)bc * TSEQ * DDIM;
  const float K1 = 0.0637587155f;  // (512^-0.5) * log2(e)
  const float K2 = -11.5415603f;   // -8 * log2(e)

  // P slot offset (conflict-free slot-XOR; same formula on write/read)
  const int poff = c * 64 + ((g ^ ((c >> 1) & 3)) << 4);

  // QK K-read offsets (R6-verified): row(ft,c), kappa swizzle
  int e0[2], e1[2];
#pragma unroll
  for (int ft = 0; ft < 2; ++ft) {
    const int row = ((c >> 2) << 3) + (ft << 2) + (c & 3);
    const int kap = ((ft << 2) | (c & 3)) ^ ((c >> 2) << 1);
    e0[ft] = row * 1024 + ((g ^ kap) << 4);
    e1[ft] = row * 1024 + (((4 + g) ^ kap) << 4);
  }

  // K staging offsets (kappa-preswizzled source)
  int soffK[4];
#pragma unroll
  for (int r = 0; r < 4; ++r) {
    const int row = wid * 4 + r;
    const int kap = (row & 7) ^ (((row >> 3) & 3) << 1);
    soffK[r] = row * 1024 + ((lane ^ kap) << 4);
  }
  const char* kgb = (const char*)(qkv + bcbase);
  const char* wtb = (const char*)W + ((size_t)bc << 20);

#pragma unroll 1
  for (int h = 0; h < 2; ++h) {
    const int qt = h == 0 ? 7 - blockIdx.y : blockIdx.y;
    const int qrow = qt * 128 + wid * 16 + c;
    const int wave_qmin = qt * 128 + wid * 16;
    const int NT = 4 * qt + 4;

    // Q fragments: lane holds Q[q = c][d = ks*32 + g*8 + j]
    bf16x8 qf[16];
    const unsigned short* qp = qkv + bcbase + (size_t)qrow * DDIM + g * 8;
#pragma unroll
    for (int ks = 0; ks < 16; ++ks) qf[ks] = *(const bf16x8*)(qp + ks * 32);

    f32x4 oacc[8][4] = {};  // O[q = qg*16 + g*4 + r][d = wid*64 + dtl*16 + c]
    float lrun = 0.0f;

    {  // prologue: stage tile 0 -> buf 0 (K swizzled; V linear from W)
      char* kb = lds;
      char* vb = lds + 65536;
#pragma unroll
      for (int r = 0; r < 4; ++r) {
        async_load16(kgb + soffK[r], kb + wid * 4096 + r * 1024 + lane * 16);
        async_load16(wtb + r * 8192 + tid * 16, vb + r * 8192 + (wid << 10));
      }
    }

    for (int kvt = 0; kvt < NT; ++kvt) {
      __syncthreads();  // A: buf[kvt&1] staged; prior P reads done
      const char* kb = lds + (kvt & 1) * 32768;
      const char* vb = lds + 65536 + (kvt & 1) * 32768;

      if (kvt + 1 < NT) {  // stage next tile; latency hides under QK phase
        char* kd = lds + ((kvt + 1) & 1) * 32768;
        char* vd = lds + 65536 + ((kvt + 1) & 1) * 32768;
        const char* ksrc = kgb + (kvt + 1) * 32768;
        const char* vsrc = wtb + (size_t)(kvt + 1) * 32768;
#pragma unroll
        for (int r = 0; r < 4; ++r) {
          async_load16(ksrc + soffK[r], kd + wid * 4096 + r * 1024 + lane * 16);
          async_load16(vsrc + r * 8192 + tid * 16, vd + r * 8192 + (wid << 10));
        }
      }

      // ---- Phase 1: QK + fixed-shift softmax + P write (own 16 q-rows)
      if (kvt * 32 <= wave_qmin + 15) {
        f32x4 stA[2] = {}, stB[2] = {};
        __builtin_amdgcn_s_setprio(1);
#pragma unroll
        for (int ks = 0; ks < 8; ++ks) {
          const int imm = (ks >> 1) * 128;
#pragma unroll
          for (int ft = 0; ft < 2; ++ft) {
            const bf16x8 kf = *(const bf16x8*)(kb + imm + ((ks & 1) ? e1[ft] : e0[ft]));
            stA[ft] = MFMA(kf, qf[ks], stA[ft]);
          }
        }
#pragma unroll
        for (int ks = 8; ks < 16; ++ks) {
          const int imm = (ks >> 1) * 128;
#pragma unroll
          for (int ft = 0; ft < 2; ++ft) {
            const bf16x8 kf = *(const bf16x8*)(kb + imm + ((ks & 1) ? e1[ft] : e0[ft]));
            stB[ft] = MFMA(kf, qf[ks], stB[ft]);
          }
        }
        __builtin_amdgcn_s_setprio(0);
        f32x4 st[2];
        st[0] = stA[0] + stB[0];
        st[1] = stA[1] + stB[1];

        float ex[2][4];
        if (kvt * 32 + 31 <= wave_qmin) {  // fully unmasked for all 16 rows
#pragma unroll
          for (int ft = 0; ft < 2; ++ft)
#pragma unroll
            for (int r = 0; r < 4; ++r)
              ex[ft][r] = exp2f(fmaf(st[ft][r], K1, K2));
        } else {  // diagonal tile: per-element causal mask
#pragma unroll
          for (int ft = 0; ft < 2; ++ft)
#pragma unroll
            for (int r = 0; r < 4; ++r) {
              const int kvg = kvt * 32 + g * 8 + ft * 4 + r;
              ex[ft][r] = (kvg > qrow) ? 0.0f : exp2f(fmaf(st[ft][r], K1, K2));
            }
        }
#pragma unroll
        for (int ft = 0; ft < 2; ++ft)
#pragma unroll
          for (int r = 0; r < 4; ++r) lrun += ex[ft][r];

        bf16x8 pa0;  // pa0[i] = P[q = c][kv = g*8 + i]
#pragma unroll
        for (int r = 0; r < 4; ++r) {
          pa0[r] = (short)f2bf(ex[0][r]);
          pa0[r + 4] = (short)f2bf(ex[1][r]);
        }
        *(bf16x8*)(Pb + wid * 1024 + poff) = pa0;
      }

      __syncthreads();  // B: P visible to all waves

      // ---- Phase 2: PV for d-slice [wid*64, wid*64+64) over all 128 q
      const char* vp = vb + (wid * 4) * 1024 + lane * 16;
      const bf16x8 v0 = *(const bf16x8*)(vp);
      const bf16x8 v1 = *(const bf16x8*)(vp + 1024);
      const bf16x8 v2 = *(const bf16x8*)(vp + 2048);
      const bf16x8 v3 = *(const bf16x8*)(vp + 3072);
#pragma unroll
      for (int qg = 0; qg < 8; ++qg) {
        if (qt * 128 + qg * 16 + 15 >= kvt * 32) {  // qg has live rows
          const bf16x8 pa = *(const bf16x8*)(Pb + qg * 1024 + poff);
          oacc[qg][0] = MFMA(pa, v0, oacc[qg][0]);
          oacc[qg][1] = MFMA(pa, v1, oacc[qg][1]);
          oacc[qg][2] = MFMA(pa, v2, oacc[qg][2]);
          oacc[qg][3] = MFMA(pa, v3, oacc[qg][3]);
        }
      }
    }

    // ---- epilogue: share denominators, then x + O/l
    float lr = lrun;
    lr += __shfl_xor(lr, 16);
    lr += __shfl_xor(lr, 32);
    if (lane < 16) ldenom[wid * 16 + lane] = 1.0f / lr;
    __syncthreads();
#pragma unroll
    for (int qg = 0; qg < 8; ++qg) {
#pragma unroll
      for (int r = 0; r < 4; ++r) {
        const float rv = ldenom[qg * 16 + g * 4 + r];
        const size_t rb =
            bcbase + (size_t)(qt * 128 + qg * 16 + g * 4 + r) * DDIM + wid * 64 + c;
#pragma unroll
        for (int dtl = 0; dtl < 4; ++dtl) {
          const size_t off = rb + dtl * 16;
          xo[off] = x[off] + oacc[qg][dtl][r] * rv;
        }
      }
    }
    __syncthreads();  // all LDS reads of half h done before half h+1 reuse
  }
}

// ---------------- cell mixing + sin pulse (in-place on d_out) ----------------
__global__ __launch_bounds__(256) void k_mix(float* __restrict__ xo,
                                             const float* __restrict__ inh,
                                             const float* __restrict__ phz,
                                             const float* __restrict__ rsc) {
  __shared__ float sI[256];
  __shared__ float sP[16];
  const int tid = threadIdx.x;
  sI[tid] = inh[tid];
  if (tid < 16) sP[tid] = phz[tid];
  __syncthreads();
  const float rs = rsc[0];
  const int idx = blockIdx.x * 256 + tid;
  const int d4 = idx & 127;
  const int t = (idx >> 7) & 1023;
  const int b = idx >> 17;
  float4* base = (float4*)xo + ((size_t)b * 16 * TSEQ + t) * 128 + d4;
  float4 v[16];
#pragma unroll
  for (int cc = 0; cc < 16; ++cc) v[cc] = base[(size_t)cc * TSEQ * 128];
#pragma unroll
  for (int k = 0; k < 16; ++k) {
    float4 comp = make_float4(0.f, 0.f, 0.f, 0.f);
#pragma unroll
    for (int cc = 0; cc < 16; ++cc) {
      const float w = sI[cc * 16 + k];
      comp.x += v[cc].x * w;
      comp.y += v[cc].y * w;
      comp.z += v[cc].z * w;
      comp.w += v[cc].w * w;
    }
    const float ph = sP[k];
    float4 o;
    o.x = v[k].x + __sinf(comp.x + ph) * rs;
    o.y = v[k].y + __sinf(comp.y + ph) * rs;
    o.z = v[k].z + __sinf(comp.z + ph) * rs;
    o.w = v[k].w + __sinf(comp.w + ph) * rs;
    base[(size_t)k * TSEQ * 128] = o;
  }
}

extern "C" void kernel_launch(void* const* d_in, const int* in_sizes, int n_in,
                              void* d_out, int out_size, void* d_ws, size_t ws_size,
                              hipStream_t stream) {
  const float* x = (const float*)d_in[0];
  // d_in[1] = causal mask -- implemented analytically
  const float* gamma = (const float*)d_in[2];
  const float* beta = (const float*)d_in[3];
  const float* Wg = (const float*)d_in[4];
  const float* inh = (const float*)d_in[5];
  const float* phz = (const float*)d_in[6];
  const float* rsc = (const float*)d_in[7];
  float* out = (float*)d_out;

  // ws (>=128MiB, confirmed): qkv (64MiB) + W (64MiB, V in PV-fragment order).
  // nx -> d_out[0:64MiB); wgb -> d_out @100MiB (dead before k_attn writes).
  unsigned short* qkv = (unsigned short*)d_ws;
  unsigned short* W = qkv + (size_t)33554432;
  unsigned short* nx = (unsigned short*)d_out;
  unsigned short* wgb = (unsigned short*)((char*)d_out + 104857600);

  k_cast<<<128, 256, 0, stream>>>(Wg, wgb, 32768);
  k_ln<<<16384, 256, 0, stream>>>(x, gamma, beta, nx);
  k_gemm<<<2048, 256, 0, stream>>>(nx, wgb, qkv, W);
  k_attn<<<dim3(64, 4), 512, 0, stream>>>(qkv, W, x, out);
  k_mix<<<2048, 256, 0, stream>>>(out, inh, phz, rsc);
}